// Round 5
// baseline (186.585 us; speedup 1.0000x reference)
//
#include <hip/hip_runtime.h>

#define B_ 32
#define N_ 8732
#define N2_ 17464
#define N4_ 4366      // N2_/4 exactly
#define C_ 21
#define NCLS 20
#define K_ 200
#define CONF_T 0.01f
#define NMS_T 0.45f
#define TPB_S 256
#define TPB_N 256
#define VCHUNK 18     // ceil(4366/256) float4 per thread
#define POOL 1024
#define HBINS 2048

typedef unsigned long long u64;
typedef unsigned int u32;

// ---------------------------------------------------------------------------
// Kernel 1 (FROZEN from R4): softmax over C=21, LDS-staged float4 loads,
// __expf + single reciprocal, LDS transpose, float4 writeout to [B,NCLS,2N].
// ---------------------------------------------------------------------------
__global__ __launch_bounds__(TPB_S) void softmax_kernel(
    const float* __restrict__ conf1, const float* __restrict__ conf2,
    float* __restrict__ scores)
{
  __shared__ float lds[TPB_S * C_];   // 21 KB
  const int t = threadIdx.x;
  const int tile = blockIdx.x * TPB_S;
  const int b = blockIdx.y;
  const int view = blockIdx.z;
  int cnt = N_ - tile; if (cnt > TPB_S) cnt = TPB_S;   // 256 or 28 (both %4==0)
  const float* conf = view ? conf2 : conf1;
  const float4* src = (const float4*)(conf + ((size_t)b * N_ + tile) * C_);
  float4* l4 = (float4*)lds;
  const int n4 = (cnt * C_) >> 2;
  for (int i = t; i < n4; i += TPB_S) l4[i] = src[i];
  __syncthreads();
  if (t < cnt) {
    float x[C_];
#pragma unroll
    for (int i = 0; i < C_; ++i) x[i] = lds[t * C_ + i];
    float m = x[0];
#pragma unroll
    for (int i = 1; i < C_; ++i) m = fmaxf(m, x[i]);
    float e[C_];
    float sum = 0.0f;
#pragma unroll
    for (int i = 0; i < C_; ++i) { e[i] = __expf(x[i] - m); sum += e[i]; }
    float inv = 1.0f / sum;
#pragma unroll
    for (int c = 1; c < C_; ++c) lds[t * C_ + (c - 1)] = e[c] * inv;
  }
  __syncthreads();
  const int nf4 = cnt >> 2;            // 64 or 7
  const int tot = NCLS * nf4;
  float* base = scores + ((size_t)b * NCLS) * N2_ + (size_t)view * N_ + tile;
  for (int f = t; f < tot; f += TPB_S) {
    int c, a0;
    if (nf4 == 64) { c = f >> 6; a0 = (f & 63) << 2; }
    else           { c = f / 7;  a0 = (f - c * 7) << 2; }
    float4 o;
    o.x = lds[(a0 + 0) * C_ + c];
    o.y = lds[(a0 + 1) * C_ + c];
    o.z = lds[(a0 + 2) * C_ + c];
    o.w = lds[(a0 + 3) * C_ + c];
    *(float4*)(base + (size_t)c * N2_ + a0) = o;
  }
}

// ---------------------------------------------------------------------------
// Kernel 2: per-(image,class). TRUE register-cached scores (asm memory
// clobber forbids rematerialization of the loads). 256 threads/block,
// launch_bounds(256,3) -> VGPR cap 170 (need ~115). Radix cutoff ->
// ballot-collect -> rank-by-count -> decode -> IoU bitmask -> scan -> compact.
// ---------------------------------------------------------------------------
__global__ __launch_bounds__(TPB_N, 3) void nms_kernel(
    const float* __restrict__ scores,
    const float4* __restrict__ loc1,
    const float4* __restrict__ loc2,
    const float4* __restrict__ dbox,
    float* __restrict__ out)
{
  const int t = threadIdx.x;
  const int lane = t & 63;
  const int wv = t >> 6;               // 0..3
  const int bimg = blockIdx.x / NCLS;
  const int cls = 1 + (blockIdx.x % NCLS);
  const float4* sc4 = (const float4*)(scores + ((size_t)bimg * NCLS + (cls - 1)) * N2_);

  __shared__ u32 hist[HBINS];            // 8 KB
  __shared__ u64 pool[POOL];             // 8 KB
  __shared__ u64 spool[256];             // 2 KB
  __shared__ float4 bb[K_];              // 3.2 KB
  __shared__ float bar[K_];
  __shared__ u64 rowmask[K_][4];         // 6.4 KB
  __shared__ u64 validmask[4];
  __shared__ u64 keepmask[4];
  __shared__ u32 wtot[4];
  __shared__ u32 sh_sel, sh_Sb, sh_Sn, sh_nc;

  // ---- load this (b,c)'s 17464 scores into registers: the ONLY global read ----
  float4 v[VCHUNK];
#pragma unroll
  for (int k = 0; k < VCHUNK; ++k) {
    int i = t + k * TPB_N;
    v[k] = (i < N4_) ? sc4[i] : make_float4(0.f, 0.f, 0.f, 0.f);
  }
  asm volatile("" ::: "memory");   // reload-after-clobber is illegal -> no remat

  // ---- multi-level radix cutoff: need <= count(key>=loKey) <= POOL ----
  u32 prefix = 0, Gacc = 0, loKey = 0;
  bool done = false;
  for (int lvl = 0; lvl < 3 && !done; ++lvl) {
    const int shift = (lvl == 0) ? 20 : (lvl == 1) ? 10 : 0;
    const u32 bmask = (lvl == 0) ? 2047u : 1023u;
    const int mshift = shift + 10;
    for (int h = t; h < HBINS; h += TPB_N) hist[h] = 0u;
    __syncthreads();
#pragma unroll
    for (int k = 0; k < VCHUNK; ++k) {
      float ss[4] = {v[k].x, v[k].y, v[k].z, v[k].w};
#pragma unroll
      for (int c2 = 0; c2 < 4; ++c2) {
        float s = ss[c2];
        if (s > CONF_T) {
          u32 key = __float_as_uint(s);
          if (lvl == 0 || (key >> mshift) == prefix)
            atomicAdd(&hist[(key >> shift) & bmask], 1u);
        }
      }
    }
    __syncthreads();
    // ---- suffix sums S[h] = sum_{h'>=h}: 8 bins/thread + wave scan ----
    u32 c[8], T = 0;
#pragma unroll
    for (int j = 0; j < 8; ++j) { c[j] = hist[8 * t + j]; T += c[j]; }
    u32 x = T;
#pragma unroll
    for (int off = 1; off < 64; off <<= 1) {
      u32 y = __shfl_down(x, off);
      if (lane + off < 64) x += y;
    }
    if (lane == 0) wtot[wv] = x;
    __syncthreads();
    u32 wafter = 0;
    for (int w = wv + 1; w < 4; ++w) wafter += wtot[w];
    u32 run = (x - T) + wafter;        // totals of threads strictly after t
#pragma unroll
    for (int j = 7; j >= 0; --j) { run += c[j]; c[j] = run; }
#pragma unroll
    for (int j = 0; j < 8; ++j) hist[8 * t + j] = c[j];
    __syncthreads();
    u32 total = hist[0];
    u32 need = (u32)K_ - Gacc;
    if (lvl == 0 && total < (u32)K_) {
      loKey = 1u;                       // undershoot: take all valid (<200)
      done = true;
    } else {
      for (int h = t; h < HBINS; h += TPB_N) {
        u32 Sb = hist[h];
        u32 Sn = (h + 1 < HBINS) ? hist[h + 1] : 0u;
        if (Sb >= need && Sn < need) { sh_sel = (u32)h; sh_Sb = Sb; sh_Sn = Sn; }
      }
      __syncthreads();
      prefix = (prefix << ((lvl == 0) ? 11 : 10)) | sh_sel;
      u32 candTotal = Gacc + sh_Sb;
      Gacc += sh_Sn;
      loKey = prefix << shift;
      done = (candTotal <= (u32)POOL) || (lvl == 2);
      __syncthreads();
    }
  }

  // ---- ballot-collect candidates (key >= loKey) into pool, 1 atomic/wave ----
  if (t == 0) sh_nc = 0u;
  __syncthreads();
#pragma unroll
  for (int k = 0; k < VCHUNK; ++k) {
    int i = t + k * TPB_N;
    float ss[4] = {v[k].x, v[k].y, v[k].z, v[k].w};
#pragma unroll
    for (int c2 = 0; c2 < 4; ++c2) {
      float s = ss[c2];
      u32 key = __float_as_uint(s);
      bool pred = (s > CONF_T) && (key >= loKey);
      u64 bal = __ballot(pred);
      if (bal) {
        u32 wb = 0;
        if (lane == 0) wb = atomicAdd(&sh_nc, (u32)__popcll(bal));
        wb = __shfl(wb, 0);
        if (pred) {
          u32 pos = wb + (u32)__popcll(bal & ((1ULL << lane) - 1ULL));
          if (pos < (u32)POOL)
            pool[pos] = ((u64)key << 32) | (u64)(0xFFFFFFFFu - (u32)(i * 4 + c2));
        }
      }
    }
  }
  __syncthreads();

  // ---- rank-by-counting: composite keys unique -> rank = #{keys > mine} ----
  u32 nc = sh_nc < (u32)POOL ? sh_nc : (u32)POOL;
  spool[t] = 0ULL;
  u64 my0 = (t < (int)nc) ? pool[t] : 0ULL;
  u64 my1 = (t + 256 < (int)nc) ? pool[t + 256] : 0ULL;
  u64 my2 = (t + 512 < (int)nc) ? pool[t + 512] : 0ULL;
  u64 my3 = (t + 768 < (int)nc) ? pool[t + 768] : 0ULL;
  __syncthreads();
  u32 r0 = 0, r1 = 0, r2 = 0, r3 = 0;
#pragma unroll 4
  for (u32 k = 0; k < nc; ++k) {        // broadcast LDS reads, barrier-free
    u64 pk = pool[k];
    r0 += (pk > my0) ? 1u : 0u;
    r1 += (pk > my1) ? 1u : 0u;
    r2 += (pk > my2) ? 1u : 0u;
    r3 += (pk > my3) ? 1u : 0u;
  }
  if (my0 != 0ULL && r0 < (u32)K_) spool[r0] = my0;
  if (my1 != 0ULL && r1 < (u32)K_) spool[r1] = my1;
  if (my2 != 0ULL && r2 < (u32)K_) spool[r2] = my2;
  if (my3 != 0ULL && r3 < (u32)K_) spool[r3] = my3;
  __syncthreads();
  // spool[0..199] == exact top_k (desc score, ties by ascending index)

  // ---- decode boxes for top-200 ----
  float x1 = 0.f, y1 = 0.f, x2 = 0.f, y2 = 0.f, area = 0.f, scv = 0.f;
  if (t < K_) {
    u64 e = spool[t];
    u32 kb = (u32)(e >> 32);
    if (kb != 0u) {
      scv = __uint_as_float(kb);
      u32 idx = 0xFFFFFFFFu - (u32)(e & 0xFFFFFFFFu);
      int nn = (idx < (u32)N_) ? (int)idx : (int)(idx - N_);
      float4 l = (idx < (u32)N_) ? loc1[(size_t)bimg * N_ + nn]
                                 : loc2[(size_t)bimg * N_ + nn];
      float4 d = dbox[nn];
      float cx = d.x + l.x * 0.1f * d.z;
      float cy = d.y + l.y * 0.1f * d.w;
      float w = d.z * __expf(l.z * 0.2f);
      float h = d.w * __expf(l.w * 0.2f);
      x1 = cx - w * 0.5f; y1 = cy - h * 0.5f;
      x2 = cx + w * 0.5f; y2 = cy + h * 0.5f;
      if (idx >= (u32)N_) {   // horizontal flip of second (TTA) view
        float tmp = 1.0f - x2; x2 = 1.0f - x1; x1 = tmp;
      }
      area = (x2 - x1) * (y2 - y1);
    }
    bb[t] = make_float4(x1, y1, x2, y2);
    bar[t] = area;
  }
  {
    bool myvalid = (t < K_) && (scv > CONF_T);
    u64 bal = __ballot(myvalid);
    if (lane == 0) validmask[wv] = bal;
  }
  __syncthreads();

  // ---- IoU>thresh bitmask rows: thread j owns full row j (4 words) ----
  if (t < K_) {
    float4 mb = bb[t];
    float ma = bar[t];
#pragma unroll
    for (int w2 = 0; w2 < 4; ++w2) {
      const int ce = (w2 == 3) ? (K_ - 192) : 64;   // 64,64,64,8
      u64 mw = 0;
      for (int j = 0; j < ce; ++j) {
        int k2 = w2 * 64 + j;
        float4 ob = bb[k2];
        float ox1 = fmaxf(mb.x, ob.x);
        float oy1 = fmaxf(mb.y, ob.y);
        float ox2 = fminf(mb.z, ob.z);
        float oy2 = fminf(mb.w, ob.w);
        float inter = fmaxf(ox2 - ox1, 0.f) * fmaxf(oy2 - oy1, 0.f);
        float uni = ma + bar[k2] - inter;
        u64 bit = (inter > NMS_T * uni) ? 1ULL : 0ULL;
        mw |= bit << j;
      }
      rowmask[t][w2] = mw;
    }
  }
  __syncthreads();

  // ---- sequential greedy scan: wave 0, replicated register state ----
  if (t < 64) {
    u64 v0 = validmask[0], v1 = validmask[1], v2 = validmask[2], v3 = validmask[3];
    u64 s0 = 0, s1 = 0, s2 = 0, s3 = 0;
    u64 k0 = 0, k1 = 0, k2m = 0, k3 = 0;
#pragma unroll 8
    for (int j = 0; j < K_; ++j) {
      u64 q0 = rowmask[j][0], q1 = rowmask[j][1], q2 = rowmask[j][2], q3 = rowmask[j][3];
      int q = j >> 6;
      u64 bit = 1ULL << (j & 63);
      u64 vw = (q == 0) ? v0 : (q == 1) ? v1 : (q == 2) ? v2 : v3;
      u64 sw = (q == 0) ? s0 : (q == 1) ? s1 : (q == 2) ? s2 : s3;
      if ((vw & bit) && !(sw & bit)) {
        s0 |= q0; s1 |= q1; s2 |= q2; s3 |= q3;
        if (q == 0) k0 |= bit; else if (q == 1) k1 |= bit;
        else if (q == 2) k2m |= bit; else k3 |= bit;
      }
    }
    if (t == 0) { keepmask[0] = k0; keepmask[1] = k1; keepmask[2] = k2m; keepmask[3] = k3; }
  }
  __syncthreads();

  // ---- compact kept entries ----
  if (t < K_) {
    int q = t >> 6, bitp = t & 63;
    u64 kw = keepmask[q];
    if ((kw >> bitp) & 1ULL) {
      int pos = (int)__popcll(kw & ((1ULL << bitp) - 1ULL));
      for (int w2 = 0; w2 < q; ++w2) pos += (int)__popcll(keepmask[w2]);
      float* o = out + ((((size_t)bimg * C_) + cls) * K_ + (size_t)pos) * 5;
      o[0] = scv; o[1] = x1; o[2] = y1; o[3] = x2; o[4] = y2;
    }
  }
}

extern "C" void kernel_launch(void* const* d_in, const int* in_sizes, int n_in,
                              void* d_out, int out_size, void* d_ws, size_t ws_size,
                              hipStream_t stream) {
  const float* loc1 = (const float*)d_in[0];
  const float* conf1 = (const float*)d_in[1];
  const float* loc2 = (const float*)d_in[2];
  const float* conf2 = (const float*)d_in[3];
  const float* dbox = (const float*)d_in[4];
  float* out = (float*)d_out;
  float* scores = (float*)d_ws;   // [B, NCLS, 2N] fp32 = 44.7 MB

  hipMemsetAsync(d_out, 0, (size_t)out_size * sizeof(float), stream);

  dim3 g1((N_ + TPB_S - 1) / TPB_S, B_, 2);
  softmax_kernel<<<g1, TPB_S, 0, stream>>>(conf1, conf2, scores);

  nms_kernel<<<B_ * NCLS, TPB_N, 0, stream>>>(
      scores, (const float4*)loc1, (const float4*)loc2, (const float4*)dbox, out);
}